// Round 9
// baseline (119.322 us; speedup 1.0000x reference)
//
#include <hip/hip_runtime.h>
#include <math.h>

#define BB 32
#define NN 1024
#define NFEAT 128
#define ALPHA 0.2f
#define MAXD 128   // max degree; Binomial(1024,0.05) mean 51, sd 7 -> P(>128) ~ 0

#define WH1_TILE_BLOCKS (BB * NN / 64)   // 512
#define ATTN_BLOCKS (BB * NN / 4)        // 8192

// ---------------- wh tile body (proven round-5): 64x64 register tile -------
template<int FIN>
__device__ __forceinline__ void wh_tile_body(
    const int blk, const int tid,
    const float* __restrict__ hin, const float* __restrict__ W,
    const float* __restrict__ a, float* __restrict__ Wh,
    float* __restrict__ f1, float* __restrict__ f2) {
  const int tx = tid & 15;
  const int ty = tid >> 4;
  const int row0 = blk * 64 + ty * 4;

  float4 acc[4];
#pragma unroll
  for (int i = 0; i < 4; ++i) acc[i] = make_float4(0.f, 0.f, 0.f, 0.f);

#pragma unroll 4
  for (int k = 0; k < FIN; k += 4) {
    float4 wv[4];
#pragma unroll
    for (int i = 0; i < 4; ++i)
      wv[i] = *reinterpret_cast<const float4*>(&W[(size_t)(k + i) * 64 + tx * 4]);
#pragma unroll
    for (int i = 0; i < 4; ++i) {
      const float4 xv = *reinterpret_cast<const float4*>(
          &hin[(size_t)(row0 + i) * FIN + k]);
      acc[i].x = fmaf(xv.x, wv[0].x, acc[i].x);
      acc[i].y = fmaf(xv.x, wv[0].y, acc[i].y);
      acc[i].z = fmaf(xv.x, wv[0].z, acc[i].z);
      acc[i].w = fmaf(xv.x, wv[0].w, acc[i].w);
      acc[i].x = fmaf(xv.y, wv[1].x, acc[i].x);
      acc[i].y = fmaf(xv.y, wv[1].y, acc[i].y);
      acc[i].z = fmaf(xv.y, wv[1].z, acc[i].z);
      acc[i].w = fmaf(xv.y, wv[1].w, acc[i].w);
      acc[i].x = fmaf(xv.z, wv[2].x, acc[i].x);
      acc[i].y = fmaf(xv.z, wv[2].y, acc[i].y);
      acc[i].z = fmaf(xv.z, wv[2].z, acc[i].z);
      acc[i].w = fmaf(xv.z, wv[2].w, acc[i].w);
      acc[i].x = fmaf(xv.w, wv[3].x, acc[i].x);
      acc[i].y = fmaf(xv.w, wv[3].y, acc[i].y);
      acc[i].z = fmaf(xv.w, wv[3].z, acc[i].z);
      acc[i].w = fmaf(xv.w, wv[3].w, acc[i].w);
    }
  }

  const float4 av1 = *reinterpret_cast<const float4*>(&a[tx * 4]);
  const float4 av2 = *reinterpret_cast<const float4*>(&a[64 + tx * 4]);
#pragma unroll
  for (int i = 0; i < 4; ++i) {
    const int row = row0 + i;
    *reinterpret_cast<float4*>(&Wh[(size_t)row * 64 + tx * 4]) = acc[i];
    float c1 = acc[i].x * av1.x + acc[i].y * av1.y + acc[i].z * av1.z + acc[i].w * av1.w;
    float c2 = acc[i].x * av2.x + acc[i].y * av2.y + acc[i].z * av2.z + acc[i].w * av2.w;
#pragma unroll
    for (int off = 8; off > 0; off >>= 1) {
      c1 += __shfl_xor(c1, off, 64);
      c2 += __shfl_xor(c2, off, 64);
    }
    if (tx == 0) { f1[row] = c1; f2[row] = c2; }
  }
}

// ---------------- Kernel W1: layer-1 projection (standalone) ---------------
__global__ __launch_bounds__(256) void wh1_kernel(
    const float* __restrict__ x, const float* __restrict__ W0,
    const float* __restrict__ a0, float* __restrict__ Wh,
    float* __restrict__ f1, float* __restrict__ f2) {
  wh_tile_body<NFEAT>(blockIdx.x, threadIdx.x, x, W0, a0, Wh, f1, f2);
}

// ---------------- Kernel N: adjacency compaction, 1 block per row ----------
// 4 waves scan 256 cols each: one float4 load + one ballot round per wave,
// LDS segment merge, single coalesced 256B store. Ascending order preserved.
__global__ __launch_bounds__(256) void nbr_build_kernel(
    const float* __restrict__ adj, unsigned short* __restrict__ nbr,
    int* __restrict__ cnt) {
  __shared__ unsigned short stageW[4][128];
  __shared__ unsigned short merged[MAXD];
  __shared__ int cnts[4];
  const int row = blockIdx.x;
  const int wv = threadIdx.x >> 6, lane = threadIdx.x & 63;
  const float* adjrow = adj + (size_t)row * NN;

  const float4 av = *reinterpret_cast<const float4*>(&adjrow[wv * 256 + lane * 4]);
  if (threadIdx.x < 64)
    reinterpret_cast<unsigned int*>(merged)[threadIdx.x] = 0u;

  const unsigned long long lmask = (1ull << lane) - 1ull;
  const int m = (av.x > 0.f ? 1 : 0) | (av.y > 0.f ? 2 : 0) |
                (av.z > 0.f ? 4 : 0) | (av.w > 0.f ? 8 : 0);
  const unsigned long long b0 = __ballot(m & 1);
  const unsigned long long b1 = __ballot(m & 2);
  const unsigned long long b2 = __ballot(m & 4);
  const unsigned long long b3 = __ballot(m & 8);
  // cols lane*4+j: all elements of lanes < this lane precede ours
  int base = __popcll(b0 & lmask) + __popcll(b1 & lmask) +
             __popcll(b2 & lmask) + __popcll(b3 & lmask);
  const int e0 = wv * 256 + lane * 4;
  if (m & 1) { if (base < 128) stageW[wv][base] = (unsigned short)(e0);     ++base; }
  if (m & 2) { if (base < 128) stageW[wv][base] = (unsigned short)(e0 + 1); ++base; }
  if (m & 4) { if (base < 128) stageW[wv][base] = (unsigned short)(e0 + 2); ++base; }
  if (m & 8) { if (base < 128) stageW[wv][base] = (unsigned short)(e0 + 3); ++base; }
  if (lane == 0)
    cnts[wv] = __popcll(b0) + __popcll(b1) + __popcll(b2) + __popcll(b3);
  __syncthreads();
  const int c0 = cnts[0], c1 = cnts[1], c2 = cnts[2], c3 = cnts[3];
  const int off = (wv == 0) ? 0 : (wv == 1) ? c0 : (wv == 2) ? c0 + c1 : c0 + c1 + c2;
  const int cw  = (wv == 0) ? c0 : (wv == 1) ? c1 : (wv == 2) ? c2 : c3;
  if (lane < cw && off + lane < MAXD) merged[off + lane] = stageW[wv][lane];
  if (64 + lane < cw && off + 64 + lane < MAXD)
    merged[off + 64 + lane] = stageW[wv][64 + lane];
  __syncthreads();
  if (threadIdx.x < 64)
    reinterpret_cast<unsigned int*>(nbr + (size_t)row * MAXD)[threadIdx.x] =
        reinterpret_cast<const unsigned int*>(merged)[threadIdx.x];
  if (threadIdx.x == 0) {
    const int total = c0 + c1 + c2 + c3;
    cnt[row] = total < MAXD ? total : MAXD;
  }
}

// ---------------- shared attn front half (softmax into LDS) ----------------
__device__ __forceinline__ void attn_softmax(
    const unsigned short* __restrict__ nrow, const int count,
    const float f1n, const float* __restrict__ f2b,
    float* ps, unsigned short* msh, const int lane) {
  int m0 = 0, m1 = 0;
  const bool on0 = lane < count, on1 = 64 + lane < count;
  float e0 = -3e38f, e1 = -3e38f;
  if (on0) { m0 = nrow[lane];      float v = f1n + f2b[m0]; e0 = v > 0.f ? v : ALPHA * v; }
  if (on1) { m1 = nrow[64 + lane]; float v = f1n + f2b[m1]; e1 = v > 0.f ? v : ALPHA * v; }
  float lmax = fmaxf(e0, e1);
#pragma unroll
  for (int off = 32; off > 0; off >>= 1) lmax = fmaxf(lmax, __shfl_xor(lmax, off, 64));
  float p0 = on0 ? __expf(e0 - lmax) : 0.f;
  float p1 = on1 ? __expf(e1 - lmax) : 0.f;
  float ls = p0 + p1;
#pragma unroll
  for (int off = 32; off > 0; off >>= 1) ls += __shfl_xor(ls, off, 64);
  const float inv = 1.f / ls;
  ps[lane] = p0 * inv;  ps[64 + lane] = p1 * inv;
  msh[lane] = (unsigned short)m0;  msh[64 + lane] = (unsigned short)m1;
}

// 8-chain gather: 8 independent L2 loads in flight per wave
__device__ __forceinline__ float attn_gather(
    const float* ps, const unsigned short* msh, const int count,
    const float* __restrict__ Whb, const int lane) {
  float a0 = 0.f, a1 = 0.f, a2 = 0.f, a3 = 0.f;
  float a4 = 0.f, a5 = 0.f, a6 = 0.f, a7 = 0.f;
  const int c8 = count & ~7;
  int k = 0;
  for (; k < c8; k += 8) {
    const float4  pa = *reinterpret_cast<const float4*>(&ps[k]);
    const float4  pb = *reinterpret_cast<const float4*>(&ps[k + 4]);
    const ushort4 ia = *reinterpret_cast<const ushort4*>(&msh[k]);
    const ushort4 ib = *reinterpret_cast<const ushort4*>(&msh[k + 4]);
    a0 = fmaf(pa.x, Whb[(size_t)ia.x * 64 + lane], a0);
    a1 = fmaf(pa.y, Whb[(size_t)ia.y * 64 + lane], a1);
    a2 = fmaf(pa.z, Whb[(size_t)ia.z * 64 + lane], a2);
    a3 = fmaf(pa.w, Whb[(size_t)ia.w * 64 + lane], a3);
    a4 = fmaf(pb.x, Whb[(size_t)ib.x * 64 + lane], a4);
    a5 = fmaf(pb.y, Whb[(size_t)ib.y * 64 + lane], a5);
    a6 = fmaf(pb.z, Whb[(size_t)ib.z * 64 + lane], a6);
    a7 = fmaf(pb.w, Whb[(size_t)ib.w * 64 + lane], a7);
  }
  for (; k < count; ++k)
    a0 = fmaf(ps[k], Whb[(size_t)msh[k] * 64 + lane], a0);
  return ((a0 + a1) + (a2 + a3)) + ((a4 + a5) + (a6 + a7));
}

// ---------------- Kernel A1: layer-1 attention + ELU + layer-2 projection --
__global__ __launch_bounds__(256) void attn1_kernel(
    const unsigned short* __restrict__ nbr, const int* __restrict__ cnt,
    const float* __restrict__ f1, const float* __restrict__ f2,
    const float* __restrict__ Wh,
    const float* __restrict__ Wnext, const float* __restrict__ anext,
    float* __restrict__ WhOut, float* __restrict__ f1o,
    float* __restrict__ f2o) {
  __shared__ float ps[4][MAXD];
  __shared__ unsigned short msh[4][MAXD];
  __shared__ float h1s[4][64];
  const int wv = threadIdx.x >> 6, lane = threadIdx.x & 63;
  // XCD swizzle: batch b -> XCD b%8; per-XCD working set ~1MB < 4MiB L2.
  const int j = blockIdx.x;
  const int batch = (j & 7) + 8 * (j >> 11);
  const int chunk = (j >> 3) & 255;
  const int row = (batch * 256 + chunk) * 4 + wv;

  int count = cnt[row];
  if (count > MAXD) count = MAXD;
  attn_softmax(nbr + (size_t)row * MAXD, count, f1[row],
               f2 + (size_t)batch * NN, ps[wv], msh[wv], lane);
  const float acc = attn_gather(ps[wv], msh[wv], count,
                                Wh + (size_t)batch * (NN * 64), lane);
  const float hval = acc > 0.f ? acc : expm1f(acc);  // ELU

  // fused layer-2 projection (wave-local LDS broadcast, Wnext L1-resident)
  h1s[wv][lane] = hval;
  float s = 0.f;
#pragma unroll 8
  for (int f = 0; f < 64; ++f)
    s = fmaf(h1s[wv][f], Wnext[f * 64 + lane], s);
  WhOut[(size_t)row * 64 + lane] = s;
  float c1 = s * anext[lane];
  float c2 = s * anext[64 + lane];
#pragma unroll
  for (int off = 32; off > 0; off >>= 1) {
    c1 += __shfl_xor(c1, off, 64);
    c2 += __shfl_xor(c2, off, 64);
  }
  if (lane == 0) { f1o[row] = c1; f2o[row] = c2; }
}

// ---------------- Kernel A2: layer-2 attention + ELU + masked partials -----
// h2 never materialized: block writes mask-weighted 4-row partial sums.
__global__ __launch_bounds__(256) void attn2_kernel(
    const unsigned short* __restrict__ nbr, const int* __restrict__ cnt,
    const float* __restrict__ f1, const float* __restrict__ f2,
    const float* __restrict__ Wh, const float* __restrict__ mask,
    float* __restrict__ part2) {
  __shared__ float ps[4][MAXD];
  __shared__ unsigned short msh[4][MAXD];
  __shared__ float agg[4][64];
  const int wv = threadIdx.x >> 6, lane = threadIdx.x & 63;
  const int j = blockIdx.x;
  const int batch = (j & 7) + 8 * (j >> 11);
  const int chunk = (j >> 3) & 255;
  const int row = (batch * 256 + chunk) * 4 + wv;

  int count = cnt[row];
  if (count > MAXD) count = MAXD;
  attn_softmax(nbr + (size_t)row * MAXD, count, f1[row],
               f2 + (size_t)batch * NN, ps[wv], msh[wv], lane);
  const float acc = attn_gather(ps[wv], msh[wv], count,
                                Wh + (size_t)batch * (NN * 64), lane);
  const float hval = acc > 0.f ? acc : expm1f(acc);  // ELU

  const float mv = mask[row];  // mask is [B,N] flat == row index
  agg[wv][lane] = mv * hval;
  __syncthreads();
  if (wv == 0)  // rows in ascending order wv=0..3: deterministic
    part2[(size_t)(batch * 256 + chunk) * 64 + lane] =
        (agg[0][lane] + agg[1][lane]) + (agg[2][lane] + agg[3][lane]);
}

// ---------------- Kernel M: finish readout + MLP ---------------------------
__global__ __launch_bounds__(256) void mlp2_kernel(
    const float* __restrict__ part2, const float* __restrict__ mask,
    const float* __restrict__ W1, const float* __restrict__ b1,
    const float* __restrict__ W2, const float* __restrict__ b2,
    float* __restrict__ outp) {
  const int b = blockIdx.x;
  const int tid = threadIdx.x;
  const int wv = tid >> 6, lane = tid & 63;
  __shared__ float aggG[4][64];
  __shared__ float msW[4];
  __shared__ float g[64];
  __shared__ float hid[128];

  // mask sum (exact: 0/1 values)
  const float4 mv4 = *reinterpret_cast<const float4*>(&mask[(size_t)b * NN + tid * 4]);
  float ms = (mv4.x + mv4.y) + (mv4.z + mv4.w);
#pragma unroll
  for (int off = 32; off > 0; off >>= 1) ms += __shfl_xor(ms, off, 64);
  if (lane == 0) msW[wv] = ms;

  // sum 256 chunk-partials per feature: thread (wv,lane) sums 64 chunks
  float gs = 0.f;
  const float* pb = part2 + ((size_t)b * 256 + wv * 64) * 64 + lane;
#pragma unroll 8
  for (int i = 0; i < 64; ++i) gs += pb[(size_t)i * 64];
  aggG[wv][lane] = gs;
  __syncthreads();
  const float denom = fmaxf((msW[0] + msW[1]) + (msW[2] + msW[3]), 1.0f);
  if (tid < 64)
    g[tid] = ((aggG[0][tid] + aggG[1][tid]) + (aggG[2][tid] + aggG[3][tid])) / denom;
  __syncthreads();
  if (tid < 128) {
    float s = b1[tid];
#pragma unroll 8
    for (int k = 0; k < 64; ++k) s += g[k] * W1[k * 128 + tid];
    hid[tid] = fmaxf(s, 0.f);
  }
  __syncthreads();
  if (tid < 2) {
    float o = b2[tid];
    for (int jj = 0; jj < 128; ++jj) o += hid[jj] * W2[jj * 2 + tid];
    outp[b * 2 + tid] = o;
  }
}

extern "C" void kernel_launch(void* const* d_in, const int* in_sizes, int n_in,
                              void* d_out, int out_size, void* d_ws, size_t ws_size,
                              hipStream_t stream) {
  const float* x      = (const float*)d_in[0];
  const float* x_mask = (const float*)d_in[1];
  const float* adj    = (const float*)d_in[2];
  const float* W0     = (const float*)d_in[3];
  const float* a0     = (const float*)d_in[4];
  const float* Wout   = (const float*)d_in[5];
  const float* aout   = (const float*)d_in[6];
  const float* W1     = (const float*)d_in[7];
  const float* b1     = (const float*)d_in[8];
  const float* W2     = (const float*)d_in[9];
  const float* b2     = (const float*)d_in[10];
  float* out = (float*)d_out;

  const int rows = BB * NN;  // 32768

  // workspace layout (~28.6 MB)
  float* ws = (float*)d_ws;
  float* Wh  = ws;                             // rows*64
  float* Wh2 = Wh + (size_t)rows * 64;         // rows*64
  float* f1  = Wh2 + (size_t)rows * 64;        // rows
  float* f2  = f1 + rows;                      // rows
  float* f1b = f2 + rows;                      // rows
  float* f2b = f1b + rows;                     // rows
  int*   cnt = (int*)(f2b + rows);             // rows ints
  unsigned short* nbr = (unsigned short*)(cnt + rows);   // rows*MAXD u16
  float* part2 = (float*)(nbr + (size_t)rows * MAXD);    // (rows/4)*64

  // K1: adjacency compaction (dedicated counters this round)
  nbr_build_kernel<<<rows, 256, 0, stream>>>(adj, nbr, cnt);
  // K2: layer-1 projection
  wh1_kernel<<<WH1_TILE_BLOCKS, 256, 0, stream>>>(x, W0, a0, Wh, f1, f2);
  // K3: layer-1 attention + ELU + fused layer-2 projection
  attn1_kernel<<<ATTN_BLOCKS, 256, 0, stream>>>(
      nbr, cnt, f1, f2, Wh, Wout, aout, Wh2, f1b, f2b);
  // K4: layer-2 attention + ELU + fused masked readout partials
  attn2_kernel<<<ATTN_BLOCKS, 256, 0, stream>>>(
      nbr, cnt, f1b, f2b, Wh2, x_mask, part2);
  // K5: finish readout + MLP
  mlp2_kernel<<<BB, 256, 0, stream>>>(part2, x_mask, W1, b1, W2, b2, out);
}

// Round 11
// 106.527 us; speedup vs baseline: 1.1201x; 1.1201x over previous
//
#include <hip/hip_runtime.h>
#include <math.h>

#define BB 32
#define NN 1024
#define NFEAT 128
#define ALPHA 0.2f
#define MAXD 128   // max degree; Binomial(1024,0.05) mean 51, sd 7 -> P(>128) ~ 0

#define WH1_TILE_BLOCKS (BB * NN / 64)   // 512
#define ATTN_BLOCKS (BB * NN / 4)        // 8192

// ---------------- wh tile body (proven round-5): 64x64 register tile -------
template<int FIN>
__device__ __forceinline__ void wh_tile_body(
    const int blk, const int tid,
    const float* __restrict__ hin, const float* __restrict__ W,
    const float* __restrict__ a, float* __restrict__ Wh,
    float* __restrict__ f1, float* __restrict__ f2) {
  const int tx = tid & 15;
  const int ty = tid >> 4;
  const int row0 = blk * 64 + ty * 4;

  float4 acc[4];
#pragma unroll
  for (int i = 0; i < 4; ++i) acc[i] = make_float4(0.f, 0.f, 0.f, 0.f);

#pragma unroll 4
  for (int k = 0; k < FIN; k += 4) {
    float4 wv[4];
#pragma unroll
    for (int i = 0; i < 4; ++i)
      wv[i] = *reinterpret_cast<const float4*>(&W[(size_t)(k + i) * 64 + tx * 4]);
#pragma unroll
    for (int i = 0; i < 4; ++i) {
      const float4 xv = *reinterpret_cast<const float4*>(
          &hin[(size_t)(row0 + i) * FIN + k]);
      acc[i].x = fmaf(xv.x, wv[0].x, acc[i].x);
      acc[i].y = fmaf(xv.x, wv[0].y, acc[i].y);
      acc[i].z = fmaf(xv.x, wv[0].z, acc[i].z);
      acc[i].w = fmaf(xv.x, wv[0].w, acc[i].w);
      acc[i].x = fmaf(xv.y, wv[1].x, acc[i].x);
      acc[i].y = fmaf(xv.y, wv[1].y, acc[i].y);
      acc[i].z = fmaf(xv.y, wv[1].z, acc[i].z);
      acc[i].w = fmaf(xv.y, wv[1].w, acc[i].w);
      acc[i].x = fmaf(xv.z, wv[2].x, acc[i].x);
      acc[i].y = fmaf(xv.z, wv[2].y, acc[i].y);
      acc[i].z = fmaf(xv.z, wv[2].z, acc[i].z);
      acc[i].w = fmaf(xv.z, wv[2].w, acc[i].w);
      acc[i].x = fmaf(xv.w, wv[3].x, acc[i].x);
      acc[i].y = fmaf(xv.w, wv[3].y, acc[i].y);
      acc[i].z = fmaf(xv.w, wv[3].z, acc[i].z);
      acc[i].w = fmaf(xv.w, wv[3].w, acc[i].w);
    }
  }

  const float4 av1 = *reinterpret_cast<const float4*>(&a[tx * 4]);
  const float4 av2 = *reinterpret_cast<const float4*>(&a[64 + tx * 4]);
#pragma unroll
  for (int i = 0; i < 4; ++i) {
    const int row = row0 + i;
    *reinterpret_cast<float4*>(&Wh[(size_t)row * 64 + tx * 4]) = acc[i];
    float c1 = acc[i].x * av1.x + acc[i].y * av1.y + acc[i].z * av1.z + acc[i].w * av1.w;
    float c2 = acc[i].x * av2.x + acc[i].y * av2.y + acc[i].z * av2.z + acc[i].w * av2.w;
#pragma unroll
    for (int off = 8; off > 0; off >>= 1) {
      c1 += __shfl_xor(c1, off, 64);
      c2 += __shfl_xor(c2, off, 64);
    }
    if (tx == 0) { f1[row] = c1; f2[row] = c2; }
  }
}

// ---------------- Kernel W1: layer-1 projection ----------------------------
__global__ __launch_bounds__(256) void wh1_kernel(
    const float* __restrict__ x, const float* __restrict__ W0,
    const float* __restrict__ a0, float* __restrict__ Wh,
    float* __restrict__ f1, float* __restrict__ f2) {
  wh_tile_body<NFEAT>(blockIdx.x, threadIdx.x, x, W0, a0, Wh, f1, f2);
}

// 8-chain gather: 8 independent L2 loads in flight per wave
__device__ __forceinline__ float attn_gather(
    const float* ps, const unsigned short* msh, const int count,
    const float* __restrict__ Whb, const int lane) {
  float a0 = 0.f, a1 = 0.f, a2 = 0.f, a3 = 0.f;
  float a4 = 0.f, a5 = 0.f, a6 = 0.f, a7 = 0.f;
  const int c8 = count & ~7;
  int k = 0;
  for (; k < c8; k += 8) {
    const float4  pa = *reinterpret_cast<const float4*>(&ps[k]);
    const float4  pb = *reinterpret_cast<const float4*>(&ps[k + 4]);
    const ushort4 ia = *reinterpret_cast<const ushort4*>(&msh[k]);
    const ushort4 ib = *reinterpret_cast<const ushort4*>(&msh[k + 4]);
    a0 = fmaf(pa.x, Whb[(size_t)ia.x * 64 + lane], a0);
    a1 = fmaf(pa.y, Whb[(size_t)ia.y * 64 + lane], a1);
    a2 = fmaf(pa.z, Whb[(size_t)ia.z * 64 + lane], a2);
    a3 = fmaf(pa.w, Whb[(size_t)ia.w * 64 + lane], a3);
    a4 = fmaf(pb.x, Whb[(size_t)ib.x * 64 + lane], a4);
    a5 = fmaf(pb.y, Whb[(size_t)ib.y * 64 + lane], a5);
    a6 = fmaf(pb.z, Whb[(size_t)ib.z * 64 + lane], a6);
    a7 = fmaf(pb.w, Whb[(size_t)ib.w * 64 + lane], a7);
  }
  for (; k < count; ++k)
    a0 = fmaf(ps[k], Whb[(size_t)msh[k] * 64 + lane], a0);
  return ((a0 + a1) + (a2 + a3)) + ((a4 + a5) + (a6 + a7));
}

// ---------------- Kernel S1: adj scan + layer-1 attn + layer-2 projection --
// Each wave: compact its adj row into LDS (ascending), run softmax+gather
// straight from the LDS list, store the list once for layer 2.
// LDS discipline: msh is written AND read as u16 only (no mixed-width LDS
// access — round-10's u32 zero-init of the u16 array was the corruption).
__global__ __launch_bounds__(256) void scan_attn1_kernel(
    const float* __restrict__ adj,
    const float* __restrict__ f1, const float* __restrict__ f2,
    const float* __restrict__ Wh,
    const float* __restrict__ Wnext, const float* __restrict__ anext,
    unsigned short* __restrict__ nbr, int* __restrict__ cnt,
    float* __restrict__ WhOut, float* __restrict__ f1o,
    float* __restrict__ f2o) {
  __shared__ float ps[4][MAXD];
  __shared__ unsigned short msh[4][MAXD];
  __shared__ float h1s[4][64];
  const int wv = threadIdx.x >> 6, lane = threadIdx.x & 63;
  // XCD swizzle: batch b -> XCD b%8; per-XCD gather set ~1MB < 4MiB L2.
  const int j = blockIdx.x;
  const int batch = (j & 7) + 8 * (j >> 11);
  const int chunk = (j >> 3) & 255;
  const int row = (batch * 256 + chunk) * 4 + wv;

  // ---- phase 1: scan & compact (wave-local, no barriers) ----
  const float* adjrow = adj + (size_t)row * NN;
  float4 av[4];
#pragma unroll
  for (int c = 0; c < 4; ++c)
    av[c] = *reinterpret_cast<const float4*>(&adjrow[c * 256 + lane * 4]);
  msh[wv][lane] = 0;            // u16 zero-init (round-8 proven pattern)
  msh[wv][64 + lane] = 0;
  const unsigned long long lmask = (1ull << lane) - 1ull;
  int count = 0;
#pragma unroll
  for (int c = 0; c < 4; ++c) {
    const int m = (av[c].x > 0.f ? 1 : 0) | (av[c].y > 0.f ? 2 : 0) |
                  (av[c].z > 0.f ? 4 : 0) | (av[c].w > 0.f ? 8 : 0);
    const unsigned long long b0 = __ballot(m & 1);
    const unsigned long long b1 = __ballot(m & 2);
    const unsigned long long b2 = __ballot(m & 4);
    const unsigned long long b3 = __ballot(m & 8);
    int base = count + __popcll(b0 & lmask) + __popcll(b1 & lmask) +
               __popcll(b2 & lmask) + __popcll(b3 & lmask);
    const int e0 = c * 256 + lane * 4;
    if (m & 1) { if (base < MAXD) msh[wv][base] = (unsigned short)(e0);     ++base; }
    if (m & 2) { if (base < MAXD) msh[wv][base] = (unsigned short)(e0 + 1); ++base; }
    if (m & 4) { if (base < MAXD) msh[wv][base] = (unsigned short)(e0 + 2); ++base; }
    if (m & 8) { if (base < MAXD) msh[wv][base] = (unsigned short)(e0 + 3); ++base; }
    count += __popcll(b0) + __popcll(b1) + __popcll(b2) + __popcll(b3);
  }
  if (count > MAXD) count = MAXD;
  if (lane == 0) cnt[row] = count;
  // persist list for layer 2: u16 LDS reads packed to one coalesced u32 store
  {
    const unsigned int lo = msh[wv][2 * lane];
    const unsigned int hi = msh[wv][2 * lane + 1];
    reinterpret_cast<unsigned int*>(nbr + (size_t)row * MAXD)[lane] =
        lo | (hi << 16);
  }

  // ---- phase 2: softmax from the LDS list ----
  const float f1n = f1[row];
  const float* f2b = f2 + (size_t)batch * NN;
  int m0 = 0, m1 = 0;
  const bool on0 = lane < count, on1 = 64 + lane < count;
  float e0v = -3e38f, e1v = -3e38f;
  if (on0) { m0 = msh[wv][lane];      float v = f1n + f2b[m0]; e0v = v > 0.f ? v : ALPHA * v; }
  if (on1) { m1 = msh[wv][64 + lane]; float v = f1n + f2b[m1]; e1v = v > 0.f ? v : ALPHA * v; }
  float lmax = fmaxf(e0v, e1v);
#pragma unroll
  for (int off = 32; off > 0; off >>= 1) lmax = fmaxf(lmax, __shfl_xor(lmax, off, 64));
  float p0 = on0 ? __expf(e0v - lmax) : 0.f;
  float p1 = on1 ? __expf(e1v - lmax) : 0.f;
  float ls = p0 + p1;
#pragma unroll
  for (int off = 32; off > 0; off >>= 1) ls += __shfl_xor(ls, off, 64);
  const float inv = 1.f / ls;
  ps[wv][lane] = p0 * inv;  ps[wv][64 + lane] = p1 * inv;

  // ---- phase 3: gather + ELU ----
  const float acc = attn_gather(ps[wv], msh[wv], count,
                                Wh + (size_t)batch * (NN * 64), lane);
  const float hval = acc > 0.f ? acc : expm1f(acc);  // ELU

  // ---- phase 4: fused layer-2 projection ----
  h1s[wv][lane] = hval;
  float s = 0.f;
#pragma unroll 8
  for (int f = 0; f < 64; ++f)
    s = fmaf(h1s[wv][f], Wnext[f * 64 + lane], s);
  WhOut[(size_t)row * 64 + lane] = s;
  float c1 = s * anext[lane];
  float c2 = s * anext[64 + lane];
#pragma unroll
  for (int off = 32; off > 0; off >>= 1) {
    c1 += __shfl_xor(c1, off, 64);
    c2 += __shfl_xor(c2, off, 64);
  }
  if (lane == 0) { f1o[row] = c1; f2o[row] = c2; }
}

// ---------------- Kernel A2: layer-2 attention + ELU + masked partials -----
__global__ __launch_bounds__(256) void attn2_kernel(
    const unsigned short* __restrict__ nbr, const int* __restrict__ cnt,
    const float* __restrict__ f1, const float* __restrict__ f2,
    const float* __restrict__ Wh, const float* __restrict__ mask,
    float* __restrict__ part2) {
  __shared__ float ps[4][MAXD];
  __shared__ unsigned short msh[4][MAXD];
  __shared__ float agg[4][64];
  const int wv = threadIdx.x >> 6, lane = threadIdx.x & 63;
  const int j = blockIdx.x;
  const int batch = (j & 7) + 8 * (j >> 11);
  const int chunk = (j >> 3) & 255;
  const int row = (batch * 256 + chunk) * 4 + wv;

  int count = cnt[row];
  if (count > MAXD) count = MAXD;
  const unsigned short* nrow = nbr + (size_t)row * MAXD;
  const float f1n = f1[row];
  const float* f2b = f2 + (size_t)batch * NN;
  int m0 = 0, m1 = 0;
  const bool on0 = lane < count, on1 = 64 + lane < count;
  float e0v = -3e38f, e1v = -3e38f;
  if (on0) { m0 = nrow[lane];      float v = f1n + f2b[m0]; e0v = v > 0.f ? v : ALPHA * v; }
  if (on1) { m1 = nrow[64 + lane]; float v = f1n + f2b[m1]; e1v = v > 0.f ? v : ALPHA * v; }
  float lmax = fmaxf(e0v, e1v);
#pragma unroll
  for (int off = 32; off > 0; off >>= 1) lmax = fmaxf(lmax, __shfl_xor(lmax, off, 64));
  float p0 = on0 ? __expf(e0v - lmax) : 0.f;
  float p1 = on1 ? __expf(e1v - lmax) : 0.f;
  float ls = p0 + p1;
#pragma unroll
  for (int off = 32; off > 0; off >>= 1) ls += __shfl_xor(ls, off, 64);
  const float inv = 1.f / ls;
  ps[wv][lane] = p0 * inv;  ps[wv][64 + lane] = p1 * inv;
  msh[wv][lane] = (unsigned short)m0;  msh[wv][64 + lane] = (unsigned short)m1;

  const float acc = attn_gather(ps[wv], msh[wv], count,
                                Wh + (size_t)batch * (NN * 64), lane);
  const float hval = acc > 0.f ? acc : expm1f(acc);  // ELU

  const float mv = mask[row];  // mask is [B,N] flat == row index
  agg[wv][lane] = mv * hval;
  __syncthreads();
  if (wv == 0)  // rows in ascending order wv=0..3: deterministic
    part2[(size_t)(batch * 256 + chunk) * 64 + lane] =
        (agg[0][lane] + agg[1][lane]) + (agg[2][lane] + agg[3][lane]);
}

// ---------------- Kernel M: finish readout + MLP ---------------------------
__global__ __launch_bounds__(256) void mlp2_kernel(
    const float* __restrict__ part2, const float* __restrict__ mask,
    const float* __restrict__ W1, const float* __restrict__ b1,
    const float* __restrict__ W2, const float* __restrict__ b2,
    float* __restrict__ outp) {
  const int b = blockIdx.x;
  const int tid = threadIdx.x;
  const int wv = tid >> 6, lane = tid & 63;
  __shared__ float aggG[4][64];
  __shared__ float msW[4];
  __shared__ float g[64];
  __shared__ float hid[128];

  // mask sum (exact: 0/1 values)
  const float4 mv4 = *reinterpret_cast<const float4*>(&mask[(size_t)b * NN + tid * 4]);
  float ms = (mv4.x + mv4.y) + (mv4.z + mv4.w);
#pragma unroll
  for (int off = 32; off > 0; off >>= 1) ms += __shfl_xor(ms, off, 64);
  if (lane == 0) msW[wv] = ms;

  // sum 256 chunk-partials per feature: thread (wv,lane) sums 64 chunks
  float gs = 0.f;
  const float* pb = part2 + ((size_t)b * 256 + wv * 64) * 64 + lane;
#pragma unroll 8
  for (int i = 0; i < 64; ++i) gs += pb[(size_t)i * 64];
  aggG[wv][lane] = gs;
  __syncthreads();
  const float denom = fmaxf((msW[0] + msW[1]) + (msW[2] + msW[3]), 1.0f);
  if (tid < 64)
    g[tid] = ((aggG[0][tid] + aggG[1][tid]) + (aggG[2][tid] + aggG[3][tid])) / denom;
  __syncthreads();
  if (tid < 128) {
    float s = b1[tid];
#pragma unroll 8
    for (int k = 0; k < 64; ++k) s += g[k] * W1[k * 128 + tid];
    hid[tid] = fmaxf(s, 0.f);
  }
  __syncthreads();
  if (tid < 2) {
    float o = b2[tid];
    for (int jj = 0; jj < 128; ++jj) o += hid[jj] * W2[jj * 2 + tid];
    outp[b * 2 + tid] = o;
  }
}

extern "C" void kernel_launch(void* const* d_in, const int* in_sizes, int n_in,
                              void* d_out, int out_size, void* d_ws, size_t ws_size,
                              hipStream_t stream) {
  const float* x      = (const float*)d_in[0];
  const float* x_mask = (const float*)d_in[1];
  const float* adj    = (const float*)d_in[2];
  const float* W0     = (const float*)d_in[3];
  const float* a0     = (const float*)d_in[4];
  const float* Wout   = (const float*)d_in[5];
  const float* aout   = (const float*)d_in[6];
  const float* W1     = (const float*)d_in[7];
  const float* b1     = (const float*)d_in[8];
  const float* W2     = (const float*)d_in[9];
  const float* b2     = (const float*)d_in[10];
  float* out = (float*)d_out;

  const int rows = BB * NN;  // 32768

  // workspace layout (~28.6 MB)
  float* ws = (float*)d_ws;
  float* Wh  = ws;                             // rows*64
  float* Wh2 = Wh + (size_t)rows * 64;         // rows*64
  float* f1  = Wh2 + (size_t)rows * 64;        // rows
  float* f2  = f1 + rows;                      // rows
  float* f1b = f2 + rows;                      // rows
  float* f2b = f1b + rows;                     // rows
  int*   cnt = (int*)(f2b + rows);             // rows ints
  unsigned short* nbr = (unsigned short*)(cnt + rows);   // rows*MAXD u16
  float* part2 = (float*)(nbr + (size_t)rows * MAXD);    // (rows/4)*64

  // K1: layer-1 projection (scan+attn1 needs f1/f2/Wh of all rows)
  wh1_kernel<<<WH1_TILE_BLOCKS, 256, 0, stream>>>(x, W0, a0, Wh, f1, f2);
  // K2: adj scan + layer-1 attention + ELU + fused layer-2 projection
  scan_attn1_kernel<<<ATTN_BLOCKS, 256, 0, stream>>>(
      adj, f1, f2, Wh, Wout, aout, nbr, cnt, Wh2, f1b, f2b);
  // K3: layer-2 attention + ELU + fused masked readout partials
  attn2_kernel<<<ATTN_BLOCKS, 256, 0, stream>>>(
      nbr, cnt, f1b, f2b, Wh2, x_mask, part2);
  // K4: finish readout + MLP
  mlp2_kernel<<<BB, 256, 0, stream>>>(part2, x_mask, W1, b1, W2, b2, out);
}

// Round 12
// 102.062 us; speedup vs baseline: 1.1691x; 1.0438x over previous
//
#include <hip/hip_runtime.h>
#include <math.h>

#define BB 32
#define NN 1024
#define NFEAT 128
#define ALPHA 0.2f
#define MAXD 128   // max degree; Binomial(1024,0.05) mean 51, sd 7 -> P(>128) ~ 0

#define WH1_TILE_BLOCKS (BB * NN / 64)   // 512
#define ATTN_BLOCKS (BB * NN / 8)        // 4096 (2 rows per wave)

// ---------------- wh tile body (proven round-5): 64x64 register tile -------
template<int FIN>
__device__ __forceinline__ void wh_tile_body(
    const int blk, const int tid,
    const float* __restrict__ hin, const float* __restrict__ W,
    const float* __restrict__ a, float* __restrict__ Wh,
    float* __restrict__ f1, float* __restrict__ f2) {
  const int tx = tid & 15;
  const int ty = tid >> 4;
  const int row0 = blk * 64 + ty * 4;

  float4 acc[4];
#pragma unroll
  for (int i = 0; i < 4; ++i) acc[i] = make_float4(0.f, 0.f, 0.f, 0.f);

#pragma unroll 4
  for (int k = 0; k < FIN; k += 4) {
    float4 wv[4];
#pragma unroll
    for (int i = 0; i < 4; ++i)
      wv[i] = *reinterpret_cast<const float4*>(&W[(size_t)(k + i) * 64 + tx * 4]);
#pragma unroll
    for (int i = 0; i < 4; ++i) {
      const float4 xv = *reinterpret_cast<const float4*>(
          &hin[(size_t)(row0 + i) * FIN + k]);
      acc[i].x = fmaf(xv.x, wv[0].x, acc[i].x);
      acc[i].y = fmaf(xv.x, wv[0].y, acc[i].y);
      acc[i].z = fmaf(xv.x, wv[0].z, acc[i].z);
      acc[i].w = fmaf(xv.x, wv[0].w, acc[i].w);
      acc[i].x = fmaf(xv.y, wv[1].x, acc[i].x);
      acc[i].y = fmaf(xv.y, wv[1].y, acc[i].y);
      acc[i].z = fmaf(xv.y, wv[1].z, acc[i].z);
      acc[i].w = fmaf(xv.y, wv[1].w, acc[i].w);
      acc[i].x = fmaf(xv.z, wv[2].x, acc[i].x);
      acc[i].y = fmaf(xv.z, wv[2].y, acc[i].y);
      acc[i].z = fmaf(xv.z, wv[2].z, acc[i].z);
      acc[i].w = fmaf(xv.z, wv[2].w, acc[i].w);
      acc[i].x = fmaf(xv.w, wv[3].x, acc[i].x);
      acc[i].y = fmaf(xv.w, wv[3].y, acc[i].y);
      acc[i].z = fmaf(xv.w, wv[3].z, acc[i].z);
      acc[i].w = fmaf(xv.w, wv[3].w, acc[i].w);
    }
  }

  const float4 av1 = *reinterpret_cast<const float4*>(&a[tx * 4]);
  const float4 av2 = *reinterpret_cast<const float4*>(&a[64 + tx * 4]);
#pragma unroll
  for (int i = 0; i < 4; ++i) {
    const int row = row0 + i;
    *reinterpret_cast<float4*>(&Wh[(size_t)row * 64 + tx * 4]) = acc[i];
    float c1 = acc[i].x * av1.x + acc[i].y * av1.y + acc[i].z * av1.z + acc[i].w * av1.w;
    float c2 = acc[i].x * av2.x + acc[i].y * av2.y + acc[i].z * av2.z + acc[i].w * av2.w;
#pragma unroll
    for (int off = 8; off > 0; off >>= 1) {
      c1 += __shfl_xor(c1, off, 64);
      c2 += __shfl_xor(c2, off, 64);
    }
    if (tx == 0) { f1[row] = c1; f2[row] = c2; }
  }
}

// ---------------- Kernel W1: layer-1 projection ----------------------------
__global__ __launch_bounds__(256) void wh1_kernel(
    const float* __restrict__ x, const float* __restrict__ W0,
    const float* __restrict__ a0, float* __restrict__ Wh,
    float* __restrict__ f1, float* __restrict__ f2) {
  wh_tile_body<NFEAT>(blockIdx.x, threadIdx.x, x, W0, a0, Wh, f1, f2);
}

// ---------------- fused 2-row gather: 8 independent loads/iter, 2 chains ---
// ps/msh are zero-padded past count -> padding contributes exactly 0.
__device__ __forceinline__ void gather2(
    const float* ps0, const unsigned short* ms0,
    const float* ps1, const unsigned short* ms1,
    const int bound, const float* __restrict__ Whb, const int lane,
    float& out0, float& out1) {
  float a0 = 0.f, a1 = 0.f, a2 = 0.f, a3 = 0.f;
  float b0 = 0.f, b1 = 0.f, b2 = 0.f, b3 = 0.f;
  for (int k = 0; k < bound; k += 4) {
    const float4  p0 = *reinterpret_cast<const float4*>(&ps0[k]);
    const ushort4 i0 = *reinterpret_cast<const ushort4*>(&ms0[k]);
    const float4  p1 = *reinterpret_cast<const float4*>(&ps1[k]);
    const ushort4 i1 = *reinterpret_cast<const ushort4*>(&ms1[k]);
    a0 = fmaf(p0.x, Whb[(size_t)i0.x * 64 + lane], a0);
    a1 = fmaf(p0.y, Whb[(size_t)i0.y * 64 + lane], a1);
    a2 = fmaf(p0.z, Whb[(size_t)i0.z * 64 + lane], a2);
    a3 = fmaf(p0.w, Whb[(size_t)i0.w * 64 + lane], a3);
    b0 = fmaf(p1.x, Whb[(size_t)i1.x * 64 + lane], b0);
    b1 = fmaf(p1.y, Whb[(size_t)i1.y * 64 + lane], b1);
    b2 = fmaf(p1.z, Whb[(size_t)i1.z * 64 + lane], b2);
    b3 = fmaf(p1.w, Whb[(size_t)i1.w * 64 + lane], b3);
  }
  out0 = (a0 + a1) + (a2 + a3);
  out1 = (b0 + b1) + (b2 + b3);
}

// ---------------- Kernel S1: adj scan + layer-1 attn + layer-2 projection --
// Each wave handles 2 rows (independent chains interleave -> latency hiding).
// LDS discipline: msh written/read as u16 only (round-10 lesson).
__global__ __launch_bounds__(256) void scan_attn1_kernel(
    const float* __restrict__ adj,
    const float* __restrict__ f1, const float* __restrict__ f2,
    const float* __restrict__ Wh,
    const float* __restrict__ Wnext, const float* __restrict__ anext,
    unsigned short* __restrict__ nbr, int* __restrict__ cnt,
    float* __restrict__ WhOut, float* __restrict__ f1o,
    float* __restrict__ f2o) {
  __shared__ float ps[4][2][MAXD];
  __shared__ unsigned short msh[4][2][MAXD];
  __shared__ float h1s[4][2][64];
  const int wv = threadIdx.x >> 6, lane = threadIdx.x & 63;
  // XCD swizzle: all blocks of a batch share j&7 -> same XCD; 4 batches/XCD.
  const int j = blockIdx.x;
  const int batch = (j & 7) + 8 * (j >> 10);
  const int cp = (j >> 3) & 127;           // chunk pair
  const int row0 = (batch * 256 + 2 * cp) * 4 + wv;   // second row = row0+4

  // ---- phase 1: load both adj rows (8x16B in flight), scan & compact ----
  float4 av[2][4];
#pragma unroll
  for (int rr = 0; rr < 2; ++rr)
#pragma unroll
    for (int c = 0; c < 4; ++c)
      av[rr][c] = *reinterpret_cast<const float4*>(
          &adj[(size_t)(row0 + rr * 4) * NN + c * 256 + lane * 4]);

#pragma unroll
  for (int rr = 0; rr < 2; ++rr) {
    msh[wv][rr][lane] = 0;
    msh[wv][rr][64 + lane] = 0;
  }

  const unsigned long long lmask = (1ull << lane) - 1ull;
  int count_r[2];
#pragma unroll
  for (int rr = 0; rr < 2; ++rr) {
    int count = 0;
#pragma unroll
    for (int c = 0; c < 4; ++c) {
      const int m = (av[rr][c].x > 0.f ? 1 : 0) | (av[rr][c].y > 0.f ? 2 : 0) |
                    (av[rr][c].z > 0.f ? 4 : 0) | (av[rr][c].w > 0.f ? 8 : 0);
      const unsigned long long b0 = __ballot(m & 1);
      const unsigned long long b1 = __ballot(m & 2);
      const unsigned long long b2 = __ballot(m & 4);
      const unsigned long long b3 = __ballot(m & 8);
      int base = count + __popcll(b0 & lmask) + __popcll(b1 & lmask) +
                 __popcll(b2 & lmask) + __popcll(b3 & lmask);
      const int e0 = c * 256 + lane * 4;
      if (m & 1) { if (base < MAXD) msh[wv][rr][base] = (unsigned short)(e0);     ++base; }
      if (m & 2) { if (base < MAXD) msh[wv][rr][base] = (unsigned short)(e0 + 1); ++base; }
      if (m & 4) { if (base < MAXD) msh[wv][rr][base] = (unsigned short)(e0 + 2); ++base; }
      if (m & 8) { if (base < MAXD) msh[wv][rr][base] = (unsigned short)(e0 + 3); ++base; }
      count += __popcll(b0) + __popcll(b1) + __popcll(b2) + __popcll(b3);
    }
    if (count > MAXD) count = MAXD;
    count_r[rr] = count;
    if (lane == 0) cnt[row0 + rr * 4] = count;
    // persist list: u16 LDS reads packed to one coalesced u32 store
    const unsigned int lo = msh[wv][rr][2 * lane];
    const unsigned int hi = msh[wv][rr][2 * lane + 1];
    reinterpret_cast<unsigned int*>(nbr + (size_t)(row0 + rr * 4) * MAXD)[lane] =
        lo | (hi << 16);
  }

  // ---- phase 2: softmax per row from the LDS lists ----
  const float* f2b = f2 + (size_t)batch * NN;
  const float f1v[2] = { f1[row0], f1[row0 + 4] };
#pragma unroll
  for (int rr = 0; rr < 2; ++rr) {
    const int cntr = count_r[rr];
    const int m0 = msh[wv][rr][lane];
    const int m1 = msh[wv][rr][64 + lane];
    const bool on0 = lane < cntr, on1 = 64 + lane < cntr;
    const float v0 = f1v[rr] + f2b[m0];   // m=0 when padded: safe load
    const float v1 = f1v[rr] + f2b[m1];
    float e0v = on0 ? (v0 > 0.f ? v0 : ALPHA * v0) : -3e38f;
    float e1v = on1 ? (v1 > 0.f ? v1 : ALPHA * v1) : -3e38f;
    float lmax = fmaxf(e0v, e1v);
#pragma unroll
    for (int off = 32; off > 0; off >>= 1) lmax = fmaxf(lmax, __shfl_xor(lmax, off, 64));
    const float p0 = on0 ? __expf(e0v - lmax) : 0.f;
    const float p1 = on1 ? __expf(e1v - lmax) : 0.f;
    float ls = p0 + p1;
#pragma unroll
    for (int off = 32; off > 0; off >>= 1) ls += __shfl_xor(ls, off, 64);
    const float inv = 1.f / ls;
    ps[wv][rr][lane] = p0 * inv;
    ps[wv][rr][64 + lane] = p1 * inv;
  }

  // ---- phase 3: fused 2-row gather + ELU ----
  const int cmax = count_r[0] > count_r[1] ? count_r[0] : count_r[1];
  const int bound = (cmax + 3) & ~3;
  const float* Whb = Wh + (size_t)batch * (NN * 64);
  float acc0, acc1;
  gather2(ps[wv][0], msh[wv][0], ps[wv][1], msh[wv][1], bound, Whb, lane,
          acc0, acc1);
  const float hv0 = acc0 > 0.f ? acc0 : expm1f(acc0);  // ELU
  const float hv1 = acc1 > 0.f ? acc1 : expm1f(acc1);

  // ---- phase 4: fused layer-2 projection (Wnext loads shared by 2 rows) ---
  h1s[wv][0][lane] = hv0;
  h1s[wv][1][lane] = hv1;
  float s0 = 0.f, s1 = 0.f;
#pragma unroll 8
  for (int f = 0; f < 64; ++f) {
    const float w = Wnext[f * 64 + lane];
    s0 = fmaf(h1s[wv][0][f], w, s0);
    s1 = fmaf(h1s[wv][1][f], w, s1);
  }
  WhOut[(size_t)row0 * 64 + lane] = s0;
  WhOut[(size_t)(row0 + 4) * 64 + lane] = s1;
  const float a1v = anext[lane], a2v = anext[64 + lane];
  float c10 = s0 * a1v, c20 = s0 * a2v;
  float c11 = s1 * a1v, c21 = s1 * a2v;
#pragma unroll
  for (int off = 32; off > 0; off >>= 1) {
    c10 += __shfl_xor(c10, off, 64);
    c20 += __shfl_xor(c20, off, 64);
    c11 += __shfl_xor(c11, off, 64);
    c21 += __shfl_xor(c21, off, 64);
  }
  if (lane == 0) {
    f1o[row0] = c10;  f2o[row0] = c20;
    f1o[row0 + 4] = c11;  f2o[row0 + 4] = c21;
  }
}

// ---------------- Kernel A2: layer-2 attention + ELU + masked partials -----
__global__ __launch_bounds__(256) void attn2_kernel(
    const unsigned short* __restrict__ nbr, const int* __restrict__ cnt,
    const float* __restrict__ f1, const float* __restrict__ f2,
    const float* __restrict__ Wh, const float* __restrict__ mask,
    float* __restrict__ part2) {
  __shared__ float ps[4][2][MAXD];
  __shared__ unsigned short msh[4][2][MAXD];
  __shared__ float agg[4][2][64];
  const int wv = threadIdx.x >> 6, lane = threadIdx.x & 63;
  const int j = blockIdx.x;
  const int batch = (j & 7) + 8 * (j >> 10);
  const int cp = (j >> 3) & 127;
  const int row0 = (batch * 256 + 2 * cp) * 4 + wv;

  const float* f2b = f2 + (size_t)batch * NN;
  const float f1v[2] = { f1[row0], f1[row0 + 4] };
  int count_r[2];
#pragma unroll
  for (int rr = 0; rr < 2; ++rr) {
    int cntr = cnt[row0 + rr * 4];
    if (cntr > MAXD) cntr = MAXD;
    count_r[rr] = cntr;
    const unsigned short* nrow = nbr + (size_t)(row0 + rr * 4) * MAXD;
    const int m0 = nrow[lane];
    const int m1 = nrow[64 + lane];
    const bool on0 = lane < cntr, on1 = 64 + lane < cntr;
    const float v0 = f1v[rr] + f2b[m0];
    const float v1 = f1v[rr] + f2b[m1];
    float e0v = on0 ? (v0 > 0.f ? v0 : ALPHA * v0) : -3e38f;
    float e1v = on1 ? (v1 > 0.f ? v1 : ALPHA * v1) : -3e38f;
    float lmax = fmaxf(e0v, e1v);
#pragma unroll
    for (int off = 32; off > 0; off >>= 1) lmax = fmaxf(lmax, __shfl_xor(lmax, off, 64));
    const float p0 = on0 ? __expf(e0v - lmax) : 0.f;
    const float p1 = on1 ? __expf(e1v - lmax) : 0.f;
    float ls = p0 + p1;
#pragma unroll
    for (int off = 32; off > 0; off >>= 1) ls += __shfl_xor(ls, off, 64);
    const float inv = 1.f / ls;
    ps[wv][rr][lane] = p0 * inv;
    ps[wv][rr][64 + lane] = p1 * inv;
    msh[wv][rr][lane] = (unsigned short)(on0 ? m0 : 0);
    msh[wv][rr][64 + lane] = (unsigned short)(on1 ? m1 : 0);
  }

  const int cmax = count_r[0] > count_r[1] ? count_r[0] : count_r[1];
  const int bound = (cmax + 3) & ~3;
  const float* Whb = Wh + (size_t)batch * (NN * 64);
  float acc0, acc1;
  gather2(ps[wv][0], msh[wv][0], ps[wv][1], msh[wv][1], bound, Whb, lane,
          acc0, acc1);
  const float hv0 = acc0 > 0.f ? acc0 : expm1f(acc0);  // ELU
  const float hv1 = acc1 > 0.f ? acc1 : expm1f(acc1);

  const float mv0 = mask[row0];
  const float mv1 = mask[row0 + 4];
  agg[wv][0][lane] = mv0 * hv0;
  agg[wv][1][lane] = mv1 * hv1;
  __syncthreads();
  if (wv < 2)  // wv==rr; rows summed in ascending wave order: deterministic
    part2[((size_t)batch * 256 + 2 * cp + wv) * 64 + lane] =
        (agg[0][wv][lane] + agg[1][wv][lane]) +
        (agg[2][wv][lane] + agg[3][wv][lane]);
}

// ---------------- Kernel M: finish readout + MLP ---------------------------
__global__ __launch_bounds__(256) void mlp2_kernel(
    const float* __restrict__ part2, const float* __restrict__ mask,
    const float* __restrict__ W1, const float* __restrict__ b1,
    const float* __restrict__ W2, const float* __restrict__ b2,
    float* __restrict__ outp) {
  const int b = blockIdx.x;
  const int tid = threadIdx.x;
  const int wv = tid >> 6, lane = tid & 63;
  __shared__ float aggG[4][64];
  __shared__ float msW[4];
  __shared__ float g[64];
  __shared__ float hid[128];

  // mask sum (exact: 0/1 values)
  const float4 mv4 = *reinterpret_cast<const float4*>(&mask[(size_t)b * NN + tid * 4]);
  float ms = (mv4.x + mv4.y) + (mv4.z + mv4.w);
#pragma unroll
  for (int off = 32; off > 0; off >>= 1) ms += __shfl_xor(ms, off, 64);
  if (lane == 0) msW[wv] = ms;

  // sum 256 chunk-partials per feature: thread (wv,lane) sums 64 chunks
  float gs = 0.f;
  const float* pb = part2 + ((size_t)b * 256 + wv * 64) * 64 + lane;
#pragma unroll 8
  for (int i = 0; i < 64; ++i) gs += pb[(size_t)i * 64];
  aggG[wv][lane] = gs;
  __syncthreads();
  const float denom = fmaxf((msW[0] + msW[1]) + (msW[2] + msW[3]), 1.0f);
  if (tid < 64)
    g[tid] = ((aggG[0][tid] + aggG[1][tid]) + (aggG[2][tid] + aggG[3][tid])) / denom;
  __syncthreads();
  if (tid < 128) {
    float s = b1[tid];
#pragma unroll 8
    for (int k = 0; k < 64; ++k) s += g[k] * W1[k * 128 + tid];
    hid[tid] = fmaxf(s, 0.f);
  }
  __syncthreads();
  if (tid < 2) {
    float o = b2[tid];
    for (int jj = 0; jj < 128; ++jj) o += hid[jj] * W2[jj * 2 + tid];
    outp[b * 2 + tid] = o;
  }
}

extern "C" void kernel_launch(void* const* d_in, const int* in_sizes, int n_in,
                              void* d_out, int out_size, void* d_ws, size_t ws_size,
                              hipStream_t stream) {
  const float* x      = (const float*)d_in[0];
  const float* x_mask = (const float*)d_in[1];
  const float* adj    = (const float*)d_in[2];
  const float* W0     = (const float*)d_in[3];
  const float* a0     = (const float*)d_in[4];
  const float* Wout   = (const float*)d_in[5];
  const float* aout   = (const float*)d_in[6];
  const float* W1     = (const float*)d_in[7];
  const float* b1     = (const float*)d_in[8];
  const float* W2     = (const float*)d_in[9];
  const float* b2     = (const float*)d_in[10];
  float* out = (float*)d_out;

  const int rows = BB * NN;  // 32768

  // workspace layout (~28.6 MB)
  float* ws = (float*)d_ws;
  float* Wh  = ws;                             // rows*64
  float* Wh2 = Wh + (size_t)rows * 64;         // rows*64
  float* f1  = Wh2 + (size_t)rows * 64;        // rows
  float* f2  = f1 + rows;                      // rows
  float* f1b = f2 + rows;                      // rows
  float* f2b = f1b + rows;                     // rows
  int*   cnt = (int*)(f2b + rows);             // rows ints
  unsigned short* nbr = (unsigned short*)(cnt + rows);   // rows*MAXD u16
  float* part2 = (float*)(nbr + (size_t)rows * MAXD);    // (rows/4)*64

  // K1: layer-1 projection (scan+attn1 needs f1/f2/Wh of all rows)
  wh1_kernel<<<WH1_TILE_BLOCKS, 256, 0, stream>>>(x, W0, a0, Wh, f1, f2);
  // K2: adj scan + layer-1 attention + ELU + fused layer-2 projection
  scan_attn1_kernel<<<ATTN_BLOCKS, 256, 0, stream>>>(
      adj, f1, f2, Wh, Wout, aout, nbr, cnt, Wh2, f1b, f2b);
  // K3: layer-2 attention + ELU + fused masked readout partials
  attn2_kernel<<<ATTN_BLOCKS, 256, 0, stream>>>(
      nbr, cnt, f1b, f2b, Wh2, x_mask, part2);
  // K4: finish readout + MLP
  mlp2_kernel<<<BB, 256, 0, stream>>>(part2, x_mask, W1, b1, W2, b2, out);
}